// Round 6
// baseline (223.154 us; speedup 1.0000x reference)
//
#include <hip/hip_runtime.h>
#include <hip/hip_bf16.h>

// B=16, H=W=64, Cin=512, K=dim=64
#define NB 16
#define HW 4096
#define CIN 512
#define KCL 64
#define BP 64                  // pixels per block (1024 blocks = 4/CU resident)
#define NCHUNK 64              // blocks per batch
#define PSTRIDE 72             // ushort stride for ft/st rows (k-major)

typedef short s16x8 __attribute__((ext_vector_type(8)));
typedef int   i32x4 __attribute__((ext_vector_type(4)));
typedef float f32x4 __attribute__((ext_vector_type(4)));

__device__ __forceinline__ unsigned short f2bf(float f) {
    unsigned u = __builtin_bit_cast(unsigned, f);
    u += 0x7fffu + ((u >> 16) & 1u);   // round-to-nearest-even
    return (unsigned short)(u >> 16);
}

__device__ __forceinline__ unsigned pk2(float lo, float hi) {
    __hip_bfloat162 h = __float22bfloat162_rn(make_float2(lo, hi));  // v_cvt_pk_bf16_f32
    unsigned r;
    __builtin_memcpy(&r, &h, 4);
    return r;
}

// prep: zero A_g+sumS_g + convert/transpose W -> Wt_g bf16 k-major [64][512]
__global__ void vlad_prep(const float* __restrict__ Wm, float* __restrict__ A_g,
                          unsigned short* __restrict__ Wt_g)
{
    const int i = blockIdx.x * 256 + threadIdx.x;
    if (i < NB * KCL * KCL + NB * KCL) A_g[i] = 0.f;   // A_g and sumS contiguous
    if (i < CIN * KCL) {
        const int c = i >> 6;
        const int n = i & 63;
        Wt_g[n * 512 + c] = f2bf(Wm[i]);
    }
}

__global__ __launch_bounds__(256, 4) void vlad_main(
    const float* __restrict__ x, const unsigned short* __restrict__ Wt_g,
    const float* __restrict__ bv, float* __restrict__ A_g,
    float* __restrict__ sumS_g)
{
    __shared__ unsigned short ft[KCL * PSTRIDE];   // F^T: [logit d][pixel p] bf16
    __shared__ unsigned short st[KCL * PSTRIDE];   // S^T: [cluster k][pixel p] bf16

    const int t = threadIdx.x;
    const int b = blockIdx.x >> 6;
    const int chunk = blockIdx.x & 63;
    const int pb = b * HW + chunk * BP;

    const int wid = t >> 6;
    const int lane = t & 63;
    const int col = lane & 15;     // MFMA A-row / B-col / D-col
    const int g = lane >> 4;       // K-slot group
    const int wpix = pb + wid * 16;   // wave owns 16 pixels (1 M-tile)

    // ---- phase 1: f = x W + b via MFMA, A-frags straight from global ----
    f32x4 acc[4];
#pragma unroll
    for (int nt = 0; nt < 4; ++nt) acc[nt] = (f32x4){0.f, 0.f, 0.f, 0.f};

    const float* xr0 = x + (size_t)(wpix + col) * CIN + g * 8;
    const unsigned short* wbase = Wt_g + col * 512 + g * 8;

#pragma unroll
    for (int kk = 0; kk < 16; ++kk) {
        const int k0 = kk * 32;
        const float4 u00 = *(const float4*)(xr0 + k0);
        const float4 u01 = *(const float4*)(xr0 + k0 + 4);
        s16x8 wf[4];
#pragma unroll
        for (int nt = 0; nt < 4; ++nt)
            wf[nt] = *(const s16x8*)(wbase + nt * (16 * 512) + k0);
        const i32x4 a0i = {(int)pk2(u00.x, u00.y), (int)pk2(u00.z, u00.w),
                           (int)pk2(u01.x, u01.y), (int)pk2(u01.z, u01.w)};
        const s16x8 a0 = __builtin_bit_cast(s16x8, a0i);
#pragma unroll
        for (int nt = 0; nt < 4; ++nt)
            acc[nt] = __builtin_amdgcn_mfma_f32_16x16x32_bf16(a0, wf[nt], acc[nt], 0, 0, 0);
    }

    // ---- bias + softmax; collect F,S; sumS in regs ----
    float bj[4];
#pragma unroll
    for (int nt = 0; nt < 4; ++nt) bj[nt] = bv[nt * 16 + col];
    float ssum[4] = {0.f, 0.f, 0.f, 0.f};
    float fv[4][4], sv[4][4];    // [nt][r]

#pragma unroll
    for (int r = 0; r < 4; ++r) {
        float v0 = acc[0][r] + bj[0];
        float v1 = acc[1][r] + bj[1];
        float v2 = acc[2][r] + bj[2];
        float v3 = acc[3][r] + bj[3];
        float m = fmaxf(fmaxf(v0, v1), fmaxf(v2, v3));
        m = fmaxf(m, __shfl_xor(m, 1));
        m = fmaxf(m, __shfl_xor(m, 2));
        m = fmaxf(m, __shfl_xor(m, 4));
        m = fmaxf(m, __shfl_xor(m, 8));
        const float e0 = __expf(v0 - m);
        const float e1 = __expf(v1 - m);
        const float e2 = __expf(v2 - m);
        const float e3 = __expf(v3 - m);
        float lsum = e0 + e1 + e2 + e3;
        lsum += __shfl_xor(lsum, 1);
        lsum += __shfl_xor(lsum, 2);
        lsum += __shfl_xor(lsum, 4);
        lsum += __shfl_xor(lsum, 8);
        const float rl = 1.0f / lsum;
        fv[0][r] = v0; fv[1][r] = v1; fv[2][r] = v2; fv[3][r] = v3;
        sv[0][r] = e0 * rl; sv[1][r] = e1 * rl; sv[2][r] = e2 * rl; sv[3][r] = e3 * rl;
        ssum[0] += sv[0][r]; ssum[1] += sv[1][r]; ssum[2] += sv[2][r]; ssum[3] += sv[3][r];
    }

    // packed b64 LDS writes: 4 consecutive pixels per row (p = wid*16 + g*4 + r)
    const int pbase = wid * 16 + g * 4;
#pragma unroll
    for (int nt = 0; nt < 4; ++nt) {
        uint2 fw, sw;
        fw.x = pk2(fv[nt][0], fv[nt][1]); fw.y = pk2(fv[nt][2], fv[nt][3]);
        sw.x = pk2(sv[nt][0], sv[nt][1]); sw.y = pk2(sv[nt][2], sv[nt][3]);
        *(uint2*)(ft + (nt * 16 + col) * PSTRIDE + pbase) = fw;
        *(uint2*)(st + (nt * 16 + col) * PSTRIDE + pbase) = sw;
    }

    // reduce ssum over the 4 K-slot groups (lane bits 4,5) -> per-wave sums
#pragma unroll
    for (int nt = 0; nt < 4; ++nt) {
        ssum[nt] += __shfl_xor(ssum[nt], 16);
        ssum[nt] += __shfl_xor(ssum[nt], 32);
    }
    if (g == 0) {
#pragma unroll
        for (int nt = 0; nt < 4; ++nt)
            atomicAdd(sumS_g + b * KCL + nt * 16 + col, ssum[nt]);
    }
    __syncthreads();

    // ---- phase 2: A[d][k] = sum_p F[p][d] S[p][k] via MFMA (K=64 pixels) ----
    f32x4 acc2[4];
#pragma unroll
    for (int nt = 0; nt < 4; ++nt) acc2[nt] = (f32x4){0.f, 0.f, 0.f, 0.f};

    const unsigned short* fta = ft + (wid * 16 + col) * PSTRIDE + g * 8;
#pragma unroll
    for (int kk = 0; kk < 2; ++kk) {
        const s16x8 af = *(const s16x8*)(fta + kk * 32);
#pragma unroll
        for (int nt = 0; nt < 4; ++nt) {
            const s16x8 bf = *(const s16x8*)(st + (nt * 16 + col) * PSTRIDE + kk * 32 + g * 8);
            acc2[nt] = __builtin_amdgcn_mfma_f32_16x16x32_bf16(af, bf, acc2[nt], 0, 0, 0);
        }
    }

    float* Ab = A_g + b * (KCL * KCL);
#pragma unroll
    for (int nt = 0; nt < 4; ++nt)
#pragma unroll
        for (int r = 0; r < 4; ++r)
            atomicAdd(Ab + (wid * 16 + g * 4 + r) * KCL + nt * 16 + col, acc2[nt][r]);
}

__global__ __launch_bounds__(256) void vlad_finalize(
    const float* __restrict__ A_g, const float* __restrict__ sumS_g,
    const float* __restrict__ Cm, float* __restrict__ out)
{
    __shared__ float red[4];
    const int b = blockIdx.x;
    const int t = threadIdx.x;
    const int k = t >> 2;
    const int dg = t & 3;
    const float sS = sumS_g[b * 64 + k];
    float v[16];
    float ssq = 0.f;
#pragma unroll
    for (int i = 0; i < 16; ++i) {
        const int d = dg * 16 + i;
        const float val = A_g[((size_t)b * 64 + d) * 64 + k] + Cm[d * 64 + k] * sS;
        v[i] = val;
        ssq += val * val;
    }
    ssq += __shfl_xor(ssq, 1);
    ssq += __shfl_xor(ssq, 2);
    const float rn = rsqrtf(fmaxf(ssq, 1e-12f));
    float gpart = 0.f;
#pragma unroll
    for (int i = 0; i < 16; ++i) {
        v[i] *= rn;
        gpart += v[i] * v[i];
    }
#pragma unroll
    for (int m = 1; m < 64; m <<= 1) gpart += __shfl_xor(gpart, m);
    if ((t & 63) == 0) red[t >> 6] = gpart;
    __syncthreads();
    const float gsq = red[0] + red[1] + red[2] + red[3];
    const float gr = rsqrtf(fmaxf(gsq, 1e-12f));
    float* o = out + (size_t)b * 4096 + k * 64 + dg * 16;
#pragma unroll
    for (int i = 0; i < 16; ++i) o[i] = v[i] * gr;
}

extern "C" void kernel_launch(void* const* d_in, const int* in_sizes, int n_in,
                              void* d_out, int out_size, void* d_ws, size_t ws_size,
                              hipStream_t stream)
{
    const float* x  = (const float*)d_in[0];  // [16,64,64,512]
    const float* Wm = (const float*)d_in[1];  // [512,64]
    const float* bv = (const float*)d_in[2];  // [64]
    const float* Cm = (const float*)d_in[3];  // [64,64]

    float* A_g = (float*)d_ws;                        // 65536 f32
    float* sumS_g = A_g + NB * KCL * KCL;             // 1024 f32
    unsigned short* Wt_g = (unsigned short*)(sumS_g + NB * KCL);  // 32768 bf16

    const int nz = NB * KCL * KCL + NB * KCL;         // 66560
    vlad_prep<<<(nz + 255) / 256, 256, 0, stream>>>(Wm, A_g, Wt_g);
    vlad_main<<<NB * NCHUNK, 256, 0, stream>>>(x, Wt_g, bv, A_g, sumS_g);
    vlad_finalize<<<NB, 256, 0, stream>>>(A_g, sumS_g, Cm, (float*)d_out);
}

// Round 7
// 213.639 us; speedup vs baseline: 1.0445x; 1.0445x over previous
//
#include <hip/hip_runtime.h>
#include <hip/hip_bf16.h>

// B=16, H=W=64, Cin=512, K=dim=64
#define NB 16
#define HW 4096
#define CIN 512
#define KCL 64
#define BP 128                 // pixels per block
#define NCHUNK 32              // blocks per batch
#define PSTR_W 520             // wt row stride (ushort): 1040 B, 16B-aligned, 2-way-free banks
#define PSTR_P 136             // ft/st row stride (ushort): 272 B, 16B-aligned

typedef short s16x8 __attribute__((ext_vector_type(8)));
typedef int   i32x4 __attribute__((ext_vector_type(4)));
typedef float f32x4 __attribute__((ext_vector_type(4)));

__device__ __forceinline__ unsigned short f2bf(float f) {
    unsigned u = __builtin_bit_cast(unsigned, f);
    u += 0x7fffu + ((u >> 16) & 1u);   // round-to-nearest-even
    return (unsigned short)(u >> 16);
}

__device__ __forceinline__ unsigned pk2(float lo, float hi) {
    __hip_bfloat162 h = __float22bfloat162_rn(make_float2(lo, hi));  // v_cvt_pk_bf16_f32
    unsigned r;
    __builtin_memcpy(&r, &h, 4);
    return r;
}

// prep: zero A_g+sumS_g + convert/transpose W -> Wt_g bf16 k-major [64][512]
__global__ void vlad_prep(const float* __restrict__ Wm, float* __restrict__ A_g,
                          unsigned short* __restrict__ Wt_g)
{
    const int i = blockIdx.x * 256 + threadIdx.x;
    if (i < NB * KCL * KCL + NB * KCL) A_g[i] = 0.f;   // A_g and sumS contiguous
    if (i < CIN * KCL) {
        const int c = i >> 6;
        const int n = i & 63;
        Wt_g[n * 512 + c] = f2bf(Wm[i]);
    }
}

// 512 threads (8 waves), grid 512 -> 2 blocks/CU, 16 waves/CU, VGPR cap 128
__global__ __launch_bounds__(512, 4) void vlad_main(
    const float* __restrict__ x, const unsigned short* __restrict__ Wt_g,
    const float* __restrict__ bv, float* __restrict__ A_g,
    float* __restrict__ sumS_g)
{
    __shared__ unsigned short smem[KCL * PSTR_W];   // 66560 B
    unsigned short* wt = smem;                      // phase 1: W^T bf16 [64][520]
    unsigned short* ft = smem;                      // phase 2: F^T [64][136] (aliases wt)
    unsigned short* st = smem + KCL * PSTR_P;       // phase 2: S^T [64][136]

    const int t = threadIdx.x;
    const int b = blockIdx.x >> 5;
    const int chunk = blockIdx.x & 31;
    const int pb = b * HW + chunk * BP;

    const int wid = t >> 6;        // 0..7
    const int lane = t & 63;
    const int col = lane & 15;     // MFMA A-row / B-col / D-col
    const int g = lane >> 4;       // K-slot group

    // ---- stage W^T into LDS (moves W off the vmcnt path -> lgkmcnt) ----
#pragma unroll
    for (int i = 0; i < 8; ++i) {
        const int idx = i * 512 + t;
        const int row = idx >> 6;
        const int c8 = (idx & 63) << 3;
        *(s16x8*)(wt + row * PSTR_W + c8) = *(const s16x8*)(Wt_g + row * 512 + c8);
    }
    __syncthreads();

    // ---- phase 1: f = x W + b via MFMA; x-frags direct from global (pure vmcnt stream) ----
    f32x4 acc[4];
#pragma unroll
    for (int nt = 0; nt < 4; ++nt) acc[nt] = (f32x4){0.f, 0.f, 0.f, 0.f};

    const float* xr0 = x + (size_t)(pb + wid * 16 + col) * CIN + g * 8;
    const unsigned short* wb = wt + col * PSTR_W + g * 8;

#pragma unroll
    for (int kk = 0; kk < 16; ++kk) {
        const int k0 = kk * 32;
        const float4 u0 = *(const float4*)(xr0 + k0);
        const float4 u1 = *(const float4*)(xr0 + k0 + 4);
        s16x8 wf[4];
#pragma unroll
        for (int nt = 0; nt < 4; ++nt)
            wf[nt] = *(const s16x8*)(wb + nt * (16 * PSTR_W) + k0);
        const i32x4 ai = {(int)pk2(u0.x, u0.y), (int)pk2(u0.z, u0.w),
                          (int)pk2(u1.x, u1.y), (int)pk2(u1.z, u1.w)};
        const s16x8 a0 = __builtin_bit_cast(s16x8, ai);
#pragma unroll
        for (int nt = 0; nt < 4; ++nt)
            acc[nt] = __builtin_amdgcn_mfma_f32_16x16x32_bf16(a0, wf[nt], acc[nt], 0, 0, 0);
    }

    // ---- bias + softmax in registers ----
    float bj[4];
#pragma unroll
    for (int nt = 0; nt < 4; ++nt) bj[nt] = bv[nt * 16 + col];
    float ssum[4] = {0.f, 0.f, 0.f, 0.f};
    float fv[4][4], sv[4][4];    // [nt][r]

#pragma unroll
    for (int r = 0; r < 4; ++r) {
        float v0 = acc[0][r] + bj[0];
        float v1 = acc[1][r] + bj[1];
        float v2 = acc[2][r] + bj[2];
        float v3 = acc[3][r] + bj[3];
        float m = fmaxf(fmaxf(v0, v1), fmaxf(v2, v3));
        m = fmaxf(m, __shfl_xor(m, 1));
        m = fmaxf(m, __shfl_xor(m, 2));
        m = fmaxf(m, __shfl_xor(m, 4));
        m = fmaxf(m, __shfl_xor(m, 8));
        const float e0 = __expf(v0 - m);
        const float e1 = __expf(v1 - m);
        const float e2 = __expf(v2 - m);
        const float e3 = __expf(v3 - m);
        float lsum = e0 + e1 + e2 + e3;
        lsum += __shfl_xor(lsum, 1);
        lsum += __shfl_xor(lsum, 2);
        lsum += __shfl_xor(lsum, 4);
        lsum += __shfl_xor(lsum, 8);
        const float rl = 1.0f / lsum;
        fv[0][r] = v0; fv[1][r] = v1; fv[2][r] = v2; fv[3][r] = v3;
        sv[0][r] = e0 * rl; sv[1][r] = e1 * rl; sv[2][r] = e2 * rl; sv[3][r] = e3 * rl;
        ssum[0] += sv[0][r]; ssum[1] += sv[1][r]; ssum[2] += sv[2][r]; ssum[3] += sv[3][r];
    }

    __syncthreads();   // all wt reads complete before ft/st alias-writes

    // packed b64 LDS writes: 4 consecutive pixels per row (p = wid*16 + g*4 + r)
    const int pbase = wid * 16 + g * 4;
#pragma unroll
    for (int nt = 0; nt < 4; ++nt) {
        uint2 fw, sw;
        fw.x = pk2(fv[nt][0], fv[nt][1]); fw.y = pk2(fv[nt][2], fv[nt][3]);
        sw.x = pk2(sv[nt][0], sv[nt][1]); sw.y = pk2(sv[nt][2], sv[nt][3]);
        *(uint2*)(ft + (nt * 16 + col) * PSTR_P + pbase) = fw;
        *(uint2*)(st + (nt * 16 + col) * PSTR_P + pbase) = sw;
    }

    // reduce ssum over lane bits 4,5 -> per-wave per-cluster mass
#pragma unroll
    for (int nt = 0; nt < 4; ++nt) {
        ssum[nt] += __shfl_xor(ssum[nt], 16);
        ssum[nt] += __shfl_xor(ssum[nt], 32);
    }
    if (g == 0) {
#pragma unroll
        for (int nt = 0; nt < 4; ++nt)
            atomicAdd(sumS_g + b * KCL + nt * 16 + col, ssum[nt]);
    }
    __syncthreads();

    // ---- phase 2: A[d][k] = sum_p F[p][d] S[p][k] via MFMA ----
    // wave -> d-tile (wid&3), pixel-half (wid>>2): K=64 pixels each
    const int dt = wid & 3;
    const int ph = wid >> 2;
    f32x4 acc2[4];
#pragma unroll
    for (int nt = 0; nt < 4; ++nt) acc2[nt] = (f32x4){0.f, 0.f, 0.f, 0.f};

    const unsigned short* fta = ft + (dt * 16 + col) * PSTR_P + ph * 64 + g * 8;
#pragma unroll
    for (int kk = 0; kk < 2; ++kk) {
        const s16x8 af = *(const s16x8*)(fta + kk * 32);
#pragma unroll
        for (int nt = 0; nt < 4; ++nt) {
            const s16x8 bf = *(const s16x8*)(st + (nt * 16 + col) * PSTR_P + ph * 64 + kk * 32 + g * 8);
            acc2[nt] = __builtin_amdgcn_mfma_f32_16x16x32_bf16(af, bf, acc2[nt], 0, 0, 0);
        }
    }

    float* Ab = A_g + b * (KCL * KCL);
#pragma unroll
    for (int nt = 0; nt < 4; ++nt)
#pragma unroll
        for (int r = 0; r < 4; ++r)
            atomicAdd(Ab + (dt * 16 + g * 4 + r) * KCL + nt * 16 + col, acc2[nt][r]);
}

__global__ __launch_bounds__(256) void vlad_finalize(
    const float* __restrict__ A_g, const float* __restrict__ sumS_g,
    const float* __restrict__ Cm, float* __restrict__ out)
{
    __shared__ float red[4];
    const int b = blockIdx.x;
    const int t = threadIdx.x;
    const int k = t >> 2;
    const int dg = t & 3;
    const float sS = sumS_g[b * 64 + k];
    float v[16];
    float ssq = 0.f;
#pragma unroll
    for (int i = 0; i < 16; ++i) {
        const int d = dg * 16 + i;
        const float val = A_g[((size_t)b * 64 + d) * 64 + k] + Cm[d * 64 + k] * sS;
        v[i] = val;
        ssq += val * val;
    }
    ssq += __shfl_xor(ssq, 1);
    ssq += __shfl_xor(ssq, 2);
    const float rn = rsqrtf(fmaxf(ssq, 1e-12f));
    float gpart = 0.f;
#pragma unroll
    for (int i = 0; i < 16; ++i) {
        v[i] *= rn;
        gpart += v[i] * v[i];
    }
#pragma unroll
    for (int m = 1; m < 64; m <<= 1) gpart += __shfl_xor(gpart, m);
    if ((t & 63) == 0) red[t >> 6] = gpart;
    __syncthreads();
    const float gsq = red[0] + red[1] + red[2] + red[3];
    const float gr = rsqrtf(fmaxf(gsq, 1e-12f));
    float* o = out + (size_t)b * 4096 + k * 64 + dg * 16;
#pragma unroll
    for (int i = 0; i < 16; ++i) o[i] = v[i] * gr;
}

extern "C" void kernel_launch(void* const* d_in, const int* in_sizes, int n_in,
                              void* d_out, int out_size, void* d_ws, size_t ws_size,
                              hipStream_t stream)
{
    const float* x  = (const float*)d_in[0];  // [16,64,64,512]
    const float* Wm = (const float*)d_in[1];  // [512,64]
    const float* bv = (const float*)d_in[2];  // [64]
    const float* Cm = (const float*)d_in[3];  // [64,64]

    float* A_g = (float*)d_ws;                        // 65536 f32
    float* sumS_g = A_g + NB * KCL * KCL;             // 1024 f32
    unsigned short* Wt_g = (unsigned short*)(sumS_g + NB * KCL);  // 32768 bf16

    const int nz = NB * KCL * KCL + NB * KCL;         // 66560
    vlad_prep<<<(nz + 255) / 256, 256, 0, stream>>>(Wm, A_g, Wt_g);
    vlad_main<<<NB * NCHUNK, 512, 0, stream>>>(x, Wt_g, bv, A_g, sumS_g);
    vlad_finalize<<<NB, 256, 0, stream>>>(A_g, sumS_g, Cm, (float*)d_out);
}

// Round 8
// 209.410 us; speedup vs baseline: 1.0656x; 1.0202x over previous
//
#include <hip/hip_runtime.h>
#include <hip/hip_bf16.h>

// B=16, H=W=64, Cin=512, K=dim=64
#define NB 16
#define HW 4096
#define CIN 512
#define KCL 64
#define BP 128                 // pixels per block
#define NCHUNK 32              // blocks per batch
#define PSTR_W 520             // wt row stride (ushort)
#define PSTR_P 136             // ft/st row stride (ushort)

typedef short s16x8 __attribute__((ext_vector_type(8)));
typedef int   i32x4 __attribute__((ext_vector_type(4)));
typedef float f32x4 __attribute__((ext_vector_type(4)));

__device__ __forceinline__ unsigned short f2bf(float f) {
    unsigned u = __builtin_bit_cast(unsigned, f);
    u += 0x7fffu + ((u >> 16) & 1u);   // round-to-nearest-even
    return (unsigned short)(u >> 16);
}

__device__ __forceinline__ unsigned pk2(float lo, float hi) {
    __hip_bfloat162 h = __float22bfloat162_rn(make_float2(lo, hi));  // v_cvt_pk_bf16_f32
    unsigned r;
    __builtin_memcpy(&r, &h, 4);
    return r;
}

// prep: zero A_g+sumS_g + convert/transpose W -> Wt_g bf16 k-major [64][512]
__global__ void vlad_prep(const float* __restrict__ Wm, float* __restrict__ A_g,
                          unsigned short* __restrict__ Wt_g)
{
    const int i = blockIdx.x * 256 + threadIdx.x;
    if (i < NB * KCL * KCL + NB * KCL) A_g[i] = 0.f;   // A_g and sumS contiguous
    if (i < CIN * KCL) {
        const int c = i >> 6;
        const int n = i & 63;
        Wt_g[n * 512 + c] = f2bf(Wm[i]);
    }
}

// 256 threads, grid 512 -> 2 blocks/CU (LDS 66.5KB), VGPR cap 256 for deep prefetch
__global__ __launch_bounds__(256, 2) void vlad_main(
    const float* __restrict__ x, const unsigned short* __restrict__ Wt_g,
    const float* __restrict__ bv, float* __restrict__ A_g,
    float* __restrict__ sumS_g)
{
    __shared__ unsigned short smem[KCL * PSTR_W];   // 66560 B
    unsigned short* wt = smem;                      // phase 1: W^T bf16 [64][520]
    unsigned short* ft = smem;                      // phase 2: F^T [64][136] (aliases wt)
    unsigned short* st = smem + KCL * PSTR_P;       // phase 2: S^T [64][136]

    const int t = threadIdx.x;
    const int b = blockIdx.x >> 5;
    const int chunk = blockIdx.x & 31;
    const int pb = b * HW + chunk * BP;

    const int wid = t >> 6;        // 0..3
    const int lane = t & 63;
    const int col = lane & 15;     // MFMA A-row / B-col / D-col
    const int g = lane >> 4;       // K-slot group

    // ---- stage W^T into LDS (W off the vmcnt path) ----
#pragma unroll
    for (int i = 0; i < 16; ++i) {
        const int idx = i * 256 + t;
        const int row = idx >> 6;
        const int c8 = (idx & 63) << 3;
        *(s16x8*)(wt + row * PSTR_W + c8) = *(const s16x8*)(Wt_g + row * 512 + c8);
    }
    __syncthreads();

    // ---- phase 1: f = x W + b via MFMA, explicit depth-4 x prefetch ----
    f32x4 acc[2][4];
#pragma unroll
    for (int mt = 0; mt < 2; ++mt)
#pragma unroll
        for (int nt = 0; nt < 4; ++nt) acc[mt][nt] = (f32x4){0.f, 0.f, 0.f, 0.f};

    const float* xp0 = x + (size_t)(pb + wid * 32 + col) * CIN + g * 8;
    const float* xp1 = xp0 + 16 * CIN;
    const unsigned short* wb = wt + col * PSTR_W + g * 8;

    float4 xb[4][4];   // [stage][mt*2+half] rotating prefetch buffer
#pragma unroll
    for (int s = 0; s < 4; ++s) {
        xb[s][0] = *(const float4*)(xp0 + s * 32);
        xb[s][1] = *(const float4*)(xp0 + s * 32 + 4);
        xb[s][2] = *(const float4*)(xp1 + s * 32);
        xb[s][3] = *(const float4*)(xp1 + s * 32 + 4);
    }

#pragma unroll
    for (int kk = 0; kk < 16; ++kk) {
        const int s = kk & 3;
        const float4 u00 = xb[s][0], u01 = xb[s][1];
        const float4 u10 = xb[s][2], u11 = xb[s][3];
        if (kk < 12) {   // issue kk+4 loads BEFORE the compute chain
            xb[s][0] = *(const float4*)(xp0 + (kk + 4) * 32);
            xb[s][1] = *(const float4*)(xp0 + (kk + 4) * 32 + 4);
            xb[s][2] = *(const float4*)(xp1 + (kk + 4) * 32);
            xb[s][3] = *(const float4*)(xp1 + (kk + 4) * 32 + 4);
        }
        const int k0 = kk * 32;
        s16x8 wf[4];
#pragma unroll
        for (int nt = 0; nt < 4; ++nt)
            wf[nt] = *(const s16x8*)(wb + nt * (16 * PSTR_W) + k0);
        const i32x4 a0i = {(int)pk2(u00.x, u00.y), (int)pk2(u00.z, u00.w),
                           (int)pk2(u01.x, u01.y), (int)pk2(u01.z, u01.w)};
        const i32x4 a1i = {(int)pk2(u10.x, u10.y), (int)pk2(u10.z, u10.w),
                           (int)pk2(u11.x, u11.y), (int)pk2(u11.z, u11.w)};
        const s16x8 a0 = __builtin_bit_cast(s16x8, a0i);
        const s16x8 a1 = __builtin_bit_cast(s16x8, a1i);
#pragma unroll
        for (int nt = 0; nt < 4; ++nt) {
            acc[0][nt] = __builtin_amdgcn_mfma_f32_16x16x32_bf16(a0, wf[nt], acc[0][nt], 0, 0, 0);
            acc[1][nt] = __builtin_amdgcn_mfma_f32_16x16x32_bf16(a1, wf[nt], acc[1][nt], 0, 0, 0);
        }
    }

    // ---- bias + softmax in registers; pack F/S to bf16 words ----
    float bj[4];
#pragma unroll
    for (int nt = 0; nt < 4; ++nt) bj[nt] = bv[nt * 16 + col];
    float ssum[4] = {0.f, 0.f, 0.f, 0.f};
    uint2 fw[2][4], sw[2][4];   // packed bf16x4 per (mt, nt)

#pragma unroll
    for (int mt = 0; mt < 2; ++mt) {
        float fvs[4][4], svs[4][4];   // [nt][r]
#pragma unroll
        for (int r = 0; r < 4; ++r) {
            float v0 = acc[mt][0][r] + bj[0];
            float v1 = acc[mt][1][r] + bj[1];
            float v2 = acc[mt][2][r] + bj[2];
            float v3 = acc[mt][3][r] + bj[3];
            float m = fmaxf(fmaxf(v0, v1), fmaxf(v2, v3));
            m = fmaxf(m, __shfl_xor(m, 1));
            m = fmaxf(m, __shfl_xor(m, 2));
            m = fmaxf(m, __shfl_xor(m, 4));
            m = fmaxf(m, __shfl_xor(m, 8));
            const float e0 = __expf(v0 - m);
            const float e1 = __expf(v1 - m);
            const float e2 = __expf(v2 - m);
            const float e3 = __expf(v3 - m);
            float lsum = e0 + e1 + e2 + e3;
            lsum += __shfl_xor(lsum, 1);
            lsum += __shfl_xor(lsum, 2);
            lsum += __shfl_xor(lsum, 4);
            lsum += __shfl_xor(lsum, 8);
            const float rl = 1.0f / lsum;
            fvs[0][r] = v0; fvs[1][r] = v1; fvs[2][r] = v2; fvs[3][r] = v3;
            svs[0][r] = e0 * rl; svs[1][r] = e1 * rl; svs[2][r] = e2 * rl; svs[3][r] = e3 * rl;
            ssum[0] += svs[0][r]; ssum[1] += svs[1][r];
            ssum[2] += svs[2][r]; ssum[3] += svs[3][r];
        }
#pragma unroll
        for (int nt = 0; nt < 4; ++nt) {
            fw[mt][nt].x = pk2(fvs[nt][0], fvs[nt][1]);
            fw[mt][nt].y = pk2(fvs[nt][2], fvs[nt][3]);
            sw[mt][nt].x = pk2(svs[nt][0], svs[nt][1]);
            sw[mt][nt].y = pk2(svs[nt][2], svs[nt][3]);
        }
    }

    __syncthreads();   // all wt reads complete before ft/st alias-writes

#pragma unroll
    for (int mt = 0; mt < 2; ++mt) {
        const int pbase = wid * 32 + mt * 16 + g * 4;
#pragma unroll
        for (int nt = 0; nt < 4; ++nt) {
            *(uint2*)(ft + (nt * 16 + col) * PSTR_P + pbase) = fw[mt][nt];
            *(uint2*)(st + (nt * 16 + col) * PSTR_P + pbase) = sw[mt][nt];
        }
    }

    // reduce ssum over lane bits 4,5 -> per-wave per-cluster mass
#pragma unroll
    for (int nt = 0; nt < 4; ++nt) {
        ssum[nt] += __shfl_xor(ssum[nt], 16);
        ssum[nt] += __shfl_xor(ssum[nt], 32);
    }
    if (g == 0) {
#pragma unroll
        for (int nt = 0; nt < 4; ++nt)
            atomicAdd(sumS_g + b * KCL + nt * 16 + col, ssum[nt]);
    }
    __syncthreads();

    // ---- phase 2: A[d][k] = sum_p F[p][d] S[p][k] via MFMA (K=128) ----
    f32x4 acc2[4];
#pragma unroll
    for (int nt = 0; nt < 4; ++nt) acc2[nt] = (f32x4){0.f, 0.f, 0.f, 0.f};

    const unsigned short* fta = ft + (wid * 16 + col) * PSTR_P + g * 8;
#pragma unroll
    for (int kk = 0; kk < 4; ++kk) {
        const s16x8 af = *(const s16x8*)(fta + kk * 32);
#pragma unroll
        for (int nt = 0; nt < 4; ++nt) {
            const s16x8 bf = *(const s16x8*)(st + (nt * 16 + col) * PSTR_P + kk * 32 + g * 8);
            acc2[nt] = __builtin_amdgcn_mfma_f32_16x16x32_bf16(af, bf, acc2[nt], 0, 0, 0);
        }
    }

    float* Ab = A_g + b * (KCL * KCL);
#pragma unroll
    for (int nt = 0; nt < 4; ++nt)
#pragma unroll
        for (int r = 0; r < 4; ++r)
            atomicAdd(Ab + (wid * 16 + g * 4 + r) * KCL + nt * 16 + col, acc2[nt][r]);
}

__global__ __launch_bounds__(256) void vlad_finalize(
    const float* __restrict__ A_g, const float* __restrict__ sumS_g,
    const float* __restrict__ Cm, float* __restrict__ out)
{
    __shared__ float red[4];
    const int b = blockIdx.x;
    const int t = threadIdx.x;
    const int k = t >> 2;
    const int dg = t & 3;
    const float sS = sumS_g[b * 64 + k];
    float v[16];
    float ssq = 0.f;
#pragma unroll
    for (int i = 0; i < 16; ++i) {
        const int d = dg * 16 + i;
        const float val = A_g[((size_t)b * 64 + d) * 64 + k] + Cm[d * 64 + k] * sS;
        v[i] = val;
        ssq += val * val;
    }
    ssq += __shfl_xor(ssq, 1);
    ssq += __shfl_xor(ssq, 2);
    const float rn = rsqrtf(fmaxf(ssq, 1e-12f));
    float gpart = 0.f;
#pragma unroll
    for (int i = 0; i < 16; ++i) {
        v[i] *= rn;
        gpart += v[i] * v[i];
    }
#pragma unroll
    for (int m = 1; m < 64; m <<= 1) gpart += __shfl_xor(gpart, m);
    if ((t & 63) == 0) red[t >> 6] = gpart;
    __syncthreads();
    const float gsq = red[0] + red[1] + red[2] + red[3];
    const float gr = rsqrtf(fmaxf(gsq, 1e-12f));
    float* o = out + (size_t)b * 4096 + k * 64 + dg * 16;
#pragma unroll
    for (int i = 0; i < 16; ++i) o[i] = v[i] * gr;
}

extern "C" void kernel_launch(void* const* d_in, const int* in_sizes, int n_in,
                              void* d_out, int out_size, void* d_ws, size_t ws_size,
                              hipStream_t stream)
{
    const float* x  = (const float*)d_in[0];  // [16,64,64,512]
    const float* Wm = (const float*)d_in[1];  // [512,64]
    const float* bv = (const float*)d_in[2];  // [64]
    const float* Cm = (const float*)d_in[3];  // [64,64]

    float* A_g = (float*)d_ws;                        // 65536 f32
    float* sumS_g = A_g + NB * KCL * KCL;             // 1024 f32
    unsigned short* Wt_g = (unsigned short*)(sumS_g + NB * KCL);  // 32768 bf16

    const int nz = NB * KCL * KCL + NB * KCL;         // 66560
    vlad_prep<<<(nz + 255) / 256, 256, 0, stream>>>(Wm, A_g, Wt_g);
    vlad_main<<<NB * NCHUNK, 256, 0, stream>>>(x, Wt_g, bv, A_g, sumS_g);
    vlad_finalize<<<NB, 256, 0, stream>>>(A_g, sumS_g, Cm, (float*)d_out);
}